// Round 8
// baseline (122.203 us; speedup 1.0000x reference)
//
#include <hip/hip_runtime.h>
#include <hip/hip_cooperative_groups.h>
#include <math.h>

namespace cg = cooperative_groups;

#define TPB 256
#define NBLK 512      // cooperative grid: 24.7KB LDS -> 6 blocks/CU max, 512 << 1536
#define SPLIT 16      // lanes per home particle
#define NGRP (TPB / SPLIT)
#define NCELL 9
#define NCELL3 729
#define CAPC 128      // bucket capacity per cell (avg ~8.4)
#define CAP 1024      // LDS staging capacity (particles); fallback if exceeded
#define PI_F 3.14159265358979323846f
#define EPS_F 1e-12f

__device__ __forceinline__ float wave_reduce(float v) {
#pragma unroll
    for (int off = 32; off > 0; off >>= 1) v += __shfl_down(v, off, 64);
    return v;
}

// valid on thread 0 only; all threads must call
__device__ __forceinline__ float block_reduce(float v, float* sbuf) {
    v = wave_reduce(v);
    int lane = threadIdx.x & 63;
    int wid  = threadIdx.x >> 6;
    if (lane == 0) sbuf[wid] = v;
    __syncthreads();
    float r = 0.0f;
    if (threadIdx.x == 0) {
        for (int w = 0; w < TPB / 64; ++w) r += sbuf[w];
    }
    return r;
}

__device__ __forceinline__ int cell_coord(float x) {
    int c = (int)floorf(x * (float)NCELL);
    return min(max(c, 0), NCELL - 1);
}

// branchless pair contribution
__device__ __forceinline__ void pair_acc(float xix, float xiy, float xiz,
                                         float vix, float viy, float viz,
                                         const float4& a, const float2& b2,
                                         float inv_h, float h2,
                                         float& wacc, float& dacc) {
    float dx = xix - a.x, dy = xiy - a.y, dz = xiz - a.z;
    float d2 = fmaf(dx, dx, fmaf(dy, dy, dz * dz));
    float r2c = fmaxf(d2, EPS_F);
    float ir  = rsqrtf(r2c);
    float r   = r2c * ir;
    float q   = r * inv_h;
    bool inm = (d2 <= h2) && (q <= 1.0f);
    bool lo  = (q <= 0.5f);
    float q2 = q * q, om = 1.0f - q, om2 = om * om;
    float w  = lo ? fmaf(6.0f, q2 * q - q2, 1.0f) : 2.0f * om2 * om;
    wacc += inm ? w : 0.0f;
    float dw = lo ? q * fmaf(18.0f, q, -12.0f) : -6.0f * om2;
    dw = inm ? dw : 0.0f;
    float irm = (d2 > EPS_F) ? ir : 0.0f;
    float dvx = a.w - vix, dvy = b2.x - viy, dvz = b2.y - viz;
    float dot = fmaf(dvx, dx, fmaf(dvy, dy, dvz * dz));
    dacc = fmaf(dw * irm, dot, dacc);
}

// ---- single fused cooperative kernel ----
__global__ void __launch_bounds__(TPB) k_fused(
    const float* __restrict__ pred, const float* __restrict__ y,
    const float* __restrict__ mid_pos, const float* __restrict__ mid_vel,
    const float* __restrict__ y_mean, const float* __restrict__ y_std,
    const float* __restrict__ h_p, const float* __restrict__ vol_p,
    const float* __restrict__ dt_p, const int* __restrict__ nb_p,
    float4* __restrict__ pos_u, float2* __restrict__ vel_u,
    int* __restrict__ items, int* __restrict__ count,
    float* __restrict__ out, int N, float invN)
{
    cg::grid_group grid = cg::this_grid();

    __shared__ float4 sh4[CAP];
    __shared__ float2 sh2[CAP];
    __shared__ int s_cid[27];
    __shared__ int s_off[28];
    __shared__ int s_hoff;
    __shared__ float sred[TPB / 64];

    int tid = threadIdx.x;
    int gid = blockIdx.x * TPB + tid;

    // ---- phase 0: zero bucket counts + out (everything later is atomicAdd) ----
    if (gid < NCELL3) count[gid] = 0;
    if (gid == NCELL3) out[0] = 0.0f;
    grid.sync();

    // ---- phase 1: per-particle compute + bucket insert + loss1 ----
    float t1 = 0.0f;
    if (gid < N) {
        int nb = nb_p[0];
        float inv_dt = 1.0f / dt_p[0];
        float y0 = y[gid * 3 + 0], y1 = y[gid * 3 + 1], y2 = y[gid * 3 + 2];
        float p0 = pred[gid * 3 + 0], p1 = pred[gid * 3 + 1], p2 = pred[gid * 3 + 2];
        float d0 = y0 - p0, d1 = y1 - p1, d2 = y2 - p2;
        t1 = fmaf(d0, d0, fmaf(d1, d1, d2 * d2));
        bool fluid = (gid >= nb);
        float i0 = fluid ? fmaf(y0, y_std[0], y_mean[0]) : 0.0f;
        float i1 = fluid ? fmaf(y1, y_std[1], y_mean[1]) : 0.0f;
        float i2 = fluid ? fmaf(y2, y_std[2], y_mean[2]) : 0.0f;
        float px = mid_pos[gid * 3 + 0] + i0;
        float py = mid_pos[gid * 3 + 1] + i1;
        float pz = mid_pos[gid * 3 + 2] + i2;
        float vx = mid_vel[gid * 3 + 0] + i0 * inv_dt;
        float vy = mid_vel[gid * 3 + 1] + i1 * inv_dt;
        float vz = mid_vel[gid * 3 + 2] + i2 * inv_dt;
        int cx = cell_coord(px), cy = cell_coord(py), cz = cell_coord(pz);
        int c = (cx * NCELL + cy) * NCELL + cz;
        pos_u[gid] = make_float4(px, py, pz, vx);
        vel_u[gid] = make_float2(vy, vz);
        int slot = atomicAdd(&count[c], 1);
        if (slot < CAPC) items[c * CAPC + slot] = gid;
    }
    float s1 = block_reduce(t1, sred);
    if (tid == 0) atomicAdd(out, s1 * invN);
    grid.sync();

    // ---- phase 2: per-cell pair sums (grid-stride over cells) ----
    float h = h_p[0], inv_h = 1.0f / h, h2 = h * h;
    float vol = vol_p[0];
    float sigma = 8.0f / (PI_F * h * h * h);

    int grp = tid >> 4;          // 0..15 (SPLIT=16)
    int s   = tid & (SPLIT - 1);
    float acc = 0.0f;

    for (int b = blockIdx.x; b < NCELL3; b += gridDim.x) {
        int cnt_home = min(count[b], CAPC);
        if (cnt_home == 0) continue;        // block-uniform

        int cz = b % NCELL, cy = (b / NCELL) % NCELL, cx = b / (NCELL * NCELL);

        // parallel neighbor-count read (one latency, not 27)
        if (tid < 27) {
            int r = tid;
            int nx = cx - 1 + r / 9;
            int ny = cy - 1 + (r / 3) % 3;
            int nz = cz - 1 + r % 3;
            bool valid = ((unsigned)nx < NCELL) && ((unsigned)ny < NCELL) &&
                         ((unsigned)nz < NCELL);
            int c = valid ? (nx * NCELL + ny) * NCELL + nz : -1;
            s_cid[r] = c;
            s_off[r] = valid ? min(count[c], CAPC) : 0;
        }
        __syncthreads();
        if (tid == 0) {
            int a = 0, hoff = 0;
            for (int r = 0; r < 27; ++r) {
                int t = s_off[r];
                s_off[r] = a;
                if (s_cid[r] == b) hoff = a;
                a += t;
            }
            s_off[27] = a;
            s_hoff = hoff;
        }
        __syncthreads();
        int T = s_off[27];
        int home_off = s_hoff;

        if (T <= CAP) {
            // flattened parallel staging: binary-search subcell per element
            for (int g = tid; g < T; g += TPB) {
                int lo = 0, hi = 26;
                while (lo < hi) {
                    int mid = (lo + hi + 1) >> 1;
                    if (s_off[mid] <= g) lo = mid; else hi = mid - 1;
                }
                int c = s_cid[lo];
                int idx = items[c * CAPC + (g - s_off[lo])];
                sh4[g] = pos_u[idx];
                sh2[g] = vel_u[idx];
            }
            __syncthreads();

            for (int hb = 0; hb < cnt_home; hb += NGRP) {
                int hp = hb + grp;
                bool hv = (hp < cnt_home);
                int hpc = home_off + (hv ? hp : 0);
                float4 me4 = sh4[hpc];
                float2 me2 = sh2[hpc];
                float wacc = 0.0f, dacc = 0.0f;
                for (int j = s; j < T; j += SPLIT) {
                    pair_acc(me4.x, me4.y, me4.z, me4.w, me2.x, me2.y,
                             sh4[j], sh2[j], inv_h, h2, wacc, dacc);
                }
#pragma unroll
                for (int o = 1; o < SPLIT; o <<= 1) {
                    wacc += __shfl_xor(wacc, o, SPLIT);
                    dacc += __shfl_xor(dacc, o, SPLIT);
                }
                if (s == 0 && hv) {
                    acc += fabsf(fmaf(vol * sigma, wacc, -1.0f))
                         + fabsf(vol * (sigma / h) * dacc);
                }
            }
        } else {
            // pathological density: direct-from-global fallback
            const int* hitm = items + (size_t)b * CAPC;
            for (int hb = 0; hb < cnt_home; hb += NGRP) {
                int hp = hb + grp;
                bool hv = (hp < cnt_home);
                int hidx = hitm[hv ? hp : 0];
                float4 me4 = pos_u[hidx];
                float2 me2 = vel_u[hidx];
                float wacc = 0.0f, dacc = 0.0f;
                for (int r = 0; r < 27; ++r) {
                    int c = s_cid[r];
                    if (c < 0) continue;
                    int cc = s_off[r + 1] - s_off[r];   // wrong for r=26? s_off[27]=T ok
                    const int* itm = items + (size_t)c * CAPC;
                    for (int j = s; j < cc; j += SPLIT) {
                        int idx = itm[j];
                        pair_acc(me4.x, me4.y, me4.z, me4.w, me2.x, me2.y,
                                 pos_u[idx], vel_u[idx], inv_h, h2, wacc, dacc);
                    }
                }
#pragma unroll
                for (int o = 1; o < SPLIT; o <<= 1) {
                    wacc += __shfl_xor(wacc, o, SPLIT);
                    dacc += __shfl_xor(dacc, o, SPLIT);
                }
                if (s == 0 && hv) {
                    acc += fabsf(fmaf(vol * sigma, wacc, -1.0f))
                         + fabsf(vol * (sigma / h) * dacc);
                }
            }
        }
        __syncthreads();   // protect s_cid/s_off/sh* before next cell iteration
    }

    float tot = block_reduce(acc, sred);
    if (tid == 0) atomicAdd(out, 0.1f * invN * tot);
}

extern "C" void kernel_launch(void* const* d_in, const int* in_sizes, int n_in,
                              void* d_out, int out_size, void* d_ws, size_t ws_size,
                              hipStream_t stream) {
    const float* pred    = (const float*)d_in[0];
    const float* y       = (const float*)d_in[1];
    const float* mid_pos = (const float*)d_in[2];
    const float* mid_vel = (const float*)d_in[3];
    const float* y_mean  = (const float*)d_in[4];
    const float* y_std   = (const float*)d_in[5];
    const float* h_p     = (const float*)d_in[6];
    const float* vol_p   = (const float*)d_in[7];
    // d_in[8] = rho_0 (cancels algebraically)
    const float* dt_p    = (const float*)d_in[9];
    const int*   nb_p    = (const int*)d_in[10];

    int N = in_sizes[0] / 3;
    float invN = 1.0f / (float)N;

    char* wsb = (char*)d_ws;
    float4* pos_u = (float4*)wsb;                 wsb += (size_t)N * sizeof(float4);
    float2* vel_u = (float2*)wsb;                 wsb += (size_t)N * sizeof(float2);
    int*    items = (int*)wsb;                    wsb += (size_t)NCELL3 * CAPC * sizeof(int);
    int*    count = (int*)wsb;

    float* out = (float*)d_out;

    void* kp[] = {
        (void*)&pred, (void*)&y, (void*)&mid_pos, (void*)&mid_vel,
        (void*)&y_mean, (void*)&y_std, (void*)&h_p, (void*)&vol_p,
        (void*)&dt_p, (void*)&nb_p,
        (void*)&pos_u, (void*)&vel_u, (void*)&items, (void*)&count,
        (void*)&out, (void*)&N, (void*)&invN
    };
    hipLaunchCooperativeKernel((void*)k_fused, dim3(NBLK), dim3(TPB),
                               kp, 0, stream);
}

// Round 9
// 23.923 us; speedup vs baseline: 5.1082x; 5.1082x over previous
//
#include <hip/hip_runtime.h>
#include <math.h>

#define TPB 256
#define NCELL 9
#define NCELL3 729
#define CAP 1024      // LDS neighborhood capacity (mean ~227, max ~300 for this input)
#define HCAP 96       // home-cell capacity (mean ~8.4)
#define PI_F 3.14159265358979323846f
#define EPS_F 1e-12f

__device__ __forceinline__ float wave_reduce(float v) {
#pragma unroll
    for (int off = 32; off > 0; off >>= 1) v += __shfl_down(v, off, 64);
    return v;
}

// valid on thread 0 only; all threads must call
template<int NT>
__device__ __forceinline__ float block_reduce(float v, float* sbuf) {
    v = wave_reduce(v);
    int lane = threadIdx.x & 63;
    int wid  = threadIdx.x >> 6;
    if (lane == 0) sbuf[wid] = v;
    __syncthreads();
    float r = 0.0f;
    if (threadIdx.x == 0) {
        for (int w = 0; w < NT / 64; ++w) r += sbuf[w];
    }
    return r;
}

__device__ __forceinline__ int cell_coord(float x) {
    int c = (int)floorf(x * (float)NCELL);
    return min(max(c, 0), NCELL - 1);
}

// ---- K1: one block per cell; self-contained scan + staged pair phase ----
__global__ void __launch_bounds__(TPB) k_main(
    const float* __restrict__ pred, const float* __restrict__ y,
    const float* __restrict__ mid_pos, const float* __restrict__ mid_vel,
    const float* __restrict__ y_mean, const float* __restrict__ y_std,
    const float* __restrict__ h_p, const float* __restrict__ vol_p,
    const float* __restrict__ dt_p, const int* __restrict__ nb_p,
    float* __restrict__ part2, float* __restrict__ l1sum, int N)
{
    __shared__ float4 sh4[CAP];      // pos.xyz, vel.x
    __shared__ float2 sh2[CAP];      // vel.yz
    __shared__ short  s_home[HCAP];  // staged index of home-cell particles
    __shared__ int    s_cnt, s_hcnt;
    __shared__ float  sred[TPB / 64];

    int b   = blockIdx.x;
    int tid = threadIdx.x;
    int cz = b % NCELL, cy = (b / NCELL) % NCELL, cx = b / (NCELL * NCELL);

    if (tid == 0) { s_cnt = 0; s_hcnt = 0; }
    __syncthreads();

    int nb = nb_p[0];
    float inv_dt = 1.0f / dt_p[0];
    float ym0 = y_mean[0], ym1 = y_mean[1], ym2 = y_mean[2];
    float ys0 = y_std[0],  ys1 = y_std[1],  ys2 = y_std[2];

    bool do_l1 = (b == 0);           // block 0 also accumulates loss1
    float t1 = 0.0f;

    // ---- phase A: scan all N, advect in registers, stage 27-cell neighborhood ----
    for (int i = tid; i < N; i += TPB) {
        float y0 = y[i * 3 + 0], y1 = y[i * 3 + 1], y2 = y[i * 3 + 2];
        float m0 = mid_pos[i * 3 + 0], m1 = mid_pos[i * 3 + 1], m2 = mid_pos[i * 3 + 2];
        if (do_l1) {
            float p0 = pred[i * 3 + 0], p1 = pred[i * 3 + 1], p2 = pred[i * 3 + 2];
            float d0 = y0 - p0, d1 = y1 - p1, d2 = y2 - p2;
            t1 = fmaf(d0, d0, fmaf(d1, d1, fmaf(d2, d2, t1)));
        }
        bool fluid = (i >= nb);
        float i0 = fluid ? fmaf(y0, ys0, ym0) : 0.0f;
        float i1 = fluid ? fmaf(y1, ys1, ym1) : 0.0f;
        float i2 = fluid ? fmaf(y2, ys2, ym2) : 0.0f;
        float px = m0 + i0, py = m1 + i1, pz = m2 + i2;
        int ix = cell_coord(px), iy = cell_coord(py), iz = cell_coord(pz);
        int dx = ix - cx, dy = iy - cy, dz = iz - cz;
        bool inN = (dx * dx <= 1) && (dy * dy <= 1) && (dz * dz <= 1);
        if (inN) {
            float v0 = mid_vel[i * 3 + 0] + i0 * inv_dt;
            float v1 = mid_vel[i * 3 + 1] + i1 * inv_dt;
            float v2 = mid_vel[i * 3 + 2] + i2 * inv_dt;
            int slot = atomicAdd(&s_cnt, 1);
            if (slot < CAP) {
                sh4[slot] = make_float4(px, py, pz, v0);
                sh2[slot] = make_float2(v1, v2);
                if ((dx | dy | dz) == 0) {
                    int hs = atomicAdd(&s_hcnt, 1);
                    if (hs < HCAP) s_home[hs] = (short)slot;
                }
            }
        }
    }
    if (do_l1) {                      // block-uniform branch (barrier inside is safe)
        float s1 = block_reduce<TPB>(t1, sred);
        if (tid == 0) l1sum[0] = s1;
    }
    __syncthreads();

    int T = min(s_cnt, CAP);
    int H = min(s_hcnt, HCAP);

    // ---- phase B: home particles (16-lane groups) vs staged neighborhood ----
    float h = h_p[0], inv_h = 1.0f / h, h2 = h * h;
    float vol = vol_p[0];
    float sigma = 8.0f / (PI_F * h * h * h);

    int grp = tid >> 4;               // 16 groups of 16 lanes
    int s   = tid & 15;
    float acc = 0.0f;

    for (int hb = 0; hb < H; hb += 16) {
        int hp = hb + grp;
        bool hv = (hp < H);
        int hidx = s_home[hv ? hp : 0];
        float4 me4 = sh4[hidx];
        float2 me2 = sh2[hidx];
        float xix = me4.x, xiy = me4.y, xiz = me4.z;
        float vix = me4.w, viy = me2.x, viz = me2.y;
        float wacc = 0.0f, dacc = 0.0f;
        for (int j = s; j < T; j += 16) {
            float4 a  = sh4[j];
            float2 b2 = sh2[j];
            float dx = xix - a.x, dy = xiy - a.y, dz = xiz - a.z;
            float d2 = fmaf(dx, dx, fmaf(dy, dy, dz * dz));
            float r2c = fmaxf(d2, EPS_F);
            float ir  = rsqrtf(r2c);
            float r   = r2c * ir;
            float q   = r * inv_h;
            bool inm = (d2 <= h2) && (q <= 1.0f);
            bool lo  = (q <= 0.5f);
            float q2 = q * q, om = 1.0f - q, om2 = om * om;
            float w  = lo ? fmaf(6.0f, q2 * q - q2, 1.0f) : 2.0f * om2 * om;
            wacc += inm ? w : 0.0f;
            float dw = lo ? q * fmaf(18.0f, q, -12.0f) : -6.0f * om2;
            dw = inm ? dw : 0.0f;
            float irm = (d2 > EPS_F) ? ir : 0.0f;
            float dvx = a.w - vix, dvy = b2.x - viy, dvz = b2.y - viz;
            float dot = fmaf(dvx, dx, fmaf(dvy, dy, dvz * dz));
            dacc = fmaf(dw * irm, dot, dacc);
        }
#pragma unroll
        for (int o = 1; o < 16; o <<= 1) {
            wacc += __shfl_xor(wacc, o, 16);
            dacc += __shfl_xor(dacc, o, 16);
        }
        if (s == 0 && hv) {
            acc += fabsf(fmaf(vol * sigma, wacc, -1.0f))     // |rho/rho0 - 1|
                 + fabsf(vol * (sigma / h) * dacc);           // |div|
        }
    }

    float tot = block_reduce<TPB>(acc, sred);
    if (tid == 0) part2[b] = tot;     // plain store, full overwrite (replay-safe)
}

// ---- K2: final combine (plain store to out, overwritten every call) ----
__global__ void __launch_bounds__(1024) k_final(
    const float* __restrict__ part2, const float* __restrict__ l1sum,
    float* __restrict__ out, float invN)
{
    __shared__ float sred[1024 / 64];
    float s = 0.0f;
    for (int k = threadIdx.x; k < NCELL3; k += 1024) s += part2[k];
    float tot = block_reduce<1024>(s, sred);
    if (threadIdx.x == 0) {
        out[0] = l1sum[0] * invN + 0.1f * invN * tot;
    }
}

extern "C" void kernel_launch(void* const* d_in, const int* in_sizes, int n_in,
                              void* d_out, int out_size, void* d_ws, size_t ws_size,
                              hipStream_t stream) {
    const float* pred    = (const float*)d_in[0];
    const float* y       = (const float*)d_in[1];
    const float* mid_pos = (const float*)d_in[2];
    const float* mid_vel = (const float*)d_in[3];
    const float* y_mean  = (const float*)d_in[4];
    const float* y_std   = (const float*)d_in[5];
    const float* h_p     = (const float*)d_in[6];
    const float* vol_p   = (const float*)d_in[7];
    // d_in[8] = rho_0 (cancels algebraically)
    const float* dt_p    = (const float*)d_in[9];
    const int*   nb_p    = (const int*)d_in[10];

    int N = in_sizes[0] / 3;
    float invN = 1.0f / (float)N;

    char* wsb = (char*)d_ws;
    float* part2 = (float*)wsb;       wsb += NCELL3 * sizeof(float);
    float* l1sum = (float*)wsb;

    k_main<<<NCELL3, TPB, 0, stream>>>(pred, y, mid_pos, mid_vel, y_mean, y_std,
                                       h_p, vol_p, dt_p, nb_p, part2, l1sum, N);

    k_final<<<1, 1024, 0, stream>>>(part2, l1sum, (float*)d_out, invN);
}

// Round 10
// 21.203 us; speedup vs baseline: 5.7634x; 1.1283x over previous
//
#include <hip/hip_runtime.h>
#include <math.h>

#define TPB 1024
#define NBLK 243       // 9 x 9 x 3: home = z-column of 3 cells
#define NWAVE (TPB / 64)
#define NCELL 9
#define CAP 1024       // LDS staging capacity (column neighborhood mean ~380)
#define HCAP 512       // home list capacity (mean ~25)
#define PI_F 3.14159265358979323846f
#define EPS_F 1e-12f

__device__ __forceinline__ float wave_reduce(float v) {
#pragma unroll
    for (int off = 32; off > 0; off >>= 1) v += __shfl_down(v, off, 64);
    return v;
}

// valid on thread 0 only; all threads must call
__device__ __forceinline__ float block_reduce(float v, float* sbuf) {
    v = wave_reduce(v);
    int lane = threadIdx.x & 63;
    int wid  = threadIdx.x >> 6;
    if (lane == 0) sbuf[wid] = v;
    __syncthreads();
    float r = 0.0f;
    if (threadIdx.x == 0) {
        for (int w = 0; w < NWAVE; ++w) r += sbuf[w];
    }
    return r;
}

__device__ __forceinline__ int cell_coord(float x) {
    int c = (int)floorf(x * (float)NCELL);
    return min(max(c, 0), NCELL - 1);
}

// branchless pair contribution vs (pos a / vel b2)
__device__ __forceinline__ void pair_math(float xix, float xiy, float xiz,
                                          float vix, float viy, float viz,
                                          float ax, float ay, float az,
                                          float bx, float by, float bz,
                                          float inv_h, float h2,
                                          float& wacc, float& dacc) {
    float dx = xix - ax, dy = xiy - ay, dz = xiz - az;
    float d2 = fmaf(dx, dx, fmaf(dy, dy, dz * dz));
    float r2c = fmaxf(d2, EPS_F);
    float ir  = rsqrtf(r2c);
    float r   = r2c * ir;
    float q   = r * inv_h;
    bool inm = (d2 <= h2) && (q <= 1.0f);
    bool lo  = (q <= 0.5f);
    float q2 = q * q, om = 1.0f - q, om2 = om * om;
    float w  = lo ? fmaf(6.0f, q2 * q - q2, 1.0f) : 2.0f * om2 * om;
    wacc += inm ? w : 0.0f;
    float dw = lo ? q * fmaf(18.0f, q, -12.0f) : -6.0f * om2;
    dw = inm ? dw : 0.0f;
    float irm = (d2 > EPS_F) ? ir : 0.0f;
    float dvx = bx - vix, dvy = by - viy, dvz = bz - viz;
    float dot = fmaf(dvx, dx, fmaf(dvy, dy, dvz * dz));
    dacc = fmaf(dw * irm, dot, dacc);
}

// ---- single kernel: self-contained scan + staged pair phase, atomicAdd out ----
__global__ void __launch_bounds__(TPB) k_main(
    const float* __restrict__ pred, const float* __restrict__ y,
    const float* __restrict__ mid_pos, const float* __restrict__ mid_vel,
    const float* __restrict__ y_mean, const float* __restrict__ y_std,
    const float* __restrict__ h_p, const float* __restrict__ vol_p,
    const float* __restrict__ dt_p, const int* __restrict__ nb_p,
    float* __restrict__ out, int N, float invN)
{
    __shared__ float4 sh4[CAP];      // pos.xyz, vel.x
    __shared__ float2 sh2[CAP];      // vel.yz
    __shared__ short  s_home[HCAP];  // GLOBAL particle index of home particles
    __shared__ int    s_cnt, s_hcnt;
    __shared__ float  sred[NWAVE];

    int b   = blockIdx.x;
    int tid = threadIdx.x;
    int cx = b / 27, cy = (b / 3) % 9, czg = b % 3;
    int z0 = 3 * czg;                // home z cells: z0 .. z0+2

    if (tid == 0) { s_cnt = 0; s_hcnt = 0; }
    __syncthreads();

    int nb = nb_p[0];
    float inv_dt = 1.0f / dt_p[0];
    float ym0 = y_mean[0], ym1 = y_mean[1], ym2 = y_mean[2];
    float ys0 = y_std[0],  ys1 = y_std[1],  ys2 = y_std[2];

    bool do_l1 = (b == 0);
    float t1 = 0.0f;
    int ln = tid & 63;
    unsigned long long lmask = (1ull << ln) - 1ull;

    // ---- phase A: scan all N (6 iters), advect in regs, wave-aggregated append ----
    for (int i = tid; i < N; i += TPB) {
        float y0 = y[i * 3 + 0], y1 = y[i * 3 + 1], y2 = y[i * 3 + 2];
        float m0 = mid_pos[i * 3 + 0], m1 = mid_pos[i * 3 + 1], m2 = mid_pos[i * 3 + 2];
        if (do_l1) {
            float p0 = pred[i * 3 + 0], p1 = pred[i * 3 + 1], p2 = pred[i * 3 + 2];
            float d0 = y0 - p0, d1 = y1 - p1, d2 = y2 - p2;
            t1 = fmaf(d0, d0, fmaf(d1, d1, fmaf(d2, d2, t1)));
        }
        bool fluid = (i >= nb);
        float i0 = fluid ? fmaf(y0, ys0, ym0) : 0.0f;
        float i1 = fluid ? fmaf(y1, ys1, ym1) : 0.0f;
        float i2 = fluid ? fmaf(y2, ys2, ym2) : 0.0f;
        float px = m0 + i0, py = m1 + i1, pz = m2 + i2;
        int ix = cell_coord(px), iy = cell_coord(py), iz = cell_coord(pz);
        int adx = abs(ix - cx), ady = abs(iy - cy);
        bool inN = (adx <= 1) && (ady <= 1) && (iz >= z0 - 1) && (iz <= z0 + 3);
        bool isH = (adx == 0) && (ady == 0) && (iz >= z0) && (iz <= z0 + 2);

        // wave-aggregated LDS append (1 atomic per wave, not per hit)
        unsigned long long mN = __ballot(inN);
        if (mN) {
            int baseN = 0;
            if (ln == 0) baseN = atomicAdd(&s_cnt, __popcll(mN));
            baseN = __shfl(baseN, 0, 64);
            if (inN) {
                int slot = baseN + __popcll(mN & lmask);
                if (slot < CAP) {
                    float v0 = mid_vel[i * 3 + 0] + i0 * inv_dt;
                    float v1 = mid_vel[i * 3 + 1] + i1 * inv_dt;
                    float v2 = mid_vel[i * 3 + 2] + i2 * inv_dt;
                    sh4[slot] = make_float4(px, py, pz, v0);
                    sh2[slot] = make_float2(v1, v2);
                }
            }
        }
        unsigned long long mH = __ballot(isH);
        if (mH) {
            int baseH = 0;
            if (ln == 0) baseH = atomicAdd(&s_hcnt, __popcll(mH));
            baseH = __shfl(baseH, 0, 64);
            if (isH) {
                int hs = baseH + __popcll(mH & lmask);
                if (hs < HCAP) s_home[hs] = (short)i;
            }
        }
    }
    if (do_l1) {                      // block-uniform branch (barrier inside is safe)
        float s1 = block_reduce(t1, sred);
        if (tid == 0) atomicAdd(out, s1 * invN);
    }
    __syncthreads();

    int T = s_cnt;
    int H = min(s_hcnt, HCAP);
    bool staged = (T <= CAP);         // block-uniform

    // ---- phase B: one wave per home particle vs staged neighborhood ----
    float h = h_p[0], inv_h = 1.0f / h, h2 = h * h;
    float vol = vol_p[0];
    float sigma = 8.0f / (PI_F * h * h * h);

    int wv = tid >> 6;
    float acc = 0.0f;

    for (int hp = wv; hp < H; hp += NWAVE) {
        int i = s_home[hp];
        // recompute home advect (wave-uniform broadcast loads)
        float y0 = y[i * 3 + 0], y1 = y[i * 3 + 1], y2 = y[i * 3 + 2];
        bool fluid = (i >= nb);
        float i0 = fluid ? fmaf(y0, ys0, ym0) : 0.0f;
        float i1 = fluid ? fmaf(y1, ys1, ym1) : 0.0f;
        float i2 = fluid ? fmaf(y2, ys2, ym2) : 0.0f;
        float xix = mid_pos[i * 3 + 0] + i0;
        float xiy = mid_pos[i * 3 + 1] + i1;
        float xiz = mid_pos[i * 3 + 2] + i2;
        float vix = mid_vel[i * 3 + 0] + i0 * inv_dt;
        float viy = mid_vel[i * 3 + 1] + i1 * inv_dt;
        float viz = mid_vel[i * 3 + 2] + i2 * inv_dt;

        float wacc = 0.0f, dacc = 0.0f;
        if (staged) {
            for (int j = ln; j < T; j += 64) {
                float4 a  = sh4[j];
                float2 b2 = sh2[j];
                pair_math(xix, xiy, xiz, vix, viy, viz,
                          a.x, a.y, a.z, a.w, b2.x, b2.y, inv_h, h2, wacc, dacc);
            }
        } else {
            // overflow fallback: rescan all N from global, recompute advect per j
            for (int j = ln; j < N; j += 64) {
                float jy0 = y[j * 3 + 0], jy1 = y[j * 3 + 1], jy2 = y[j * 3 + 2];
                bool jf = (j >= nb);
                float j0 = jf ? fmaf(jy0, ys0, ym0) : 0.0f;
                float j1 = jf ? fmaf(jy1, ys1, ym1) : 0.0f;
                float j2 = jf ? fmaf(jy2, ys2, ym2) : 0.0f;
                float ax = mid_pos[j * 3 + 0] + j0;
                float ay = mid_pos[j * 3 + 1] + j1;
                float az = mid_pos[j * 3 + 2] + j2;
                float bx = mid_vel[j * 3 + 0] + j0 * inv_dt;
                float by = mid_vel[j * 3 + 1] + j1 * inv_dt;
                float bz = mid_vel[j * 3 + 2] + j2 * inv_dt;
                pair_math(xix, xiy, xiz, vix, viy, viz,
                          ax, ay, az, bx, by, bz, inv_h, h2, wacc, dacc);
            }
        }
        wacc = wave_reduce(wacc);
        dacc = wave_reduce(dacc);
        if (ln == 0) {
            acc += fabsf(fmaf(vol * sigma, wacc, -1.0f))   // |rho/rho0 - 1|
                 + fabsf(vol * (sigma / h) * dacc);         // |div|
        }
    }

    float tot = block_reduce(acc, sred);
    if (tid == 0) atomicAdd(out, 0.1f * invN * tot);   // device-scope atomic
}

extern "C" void kernel_launch(void* const* d_in, const int* in_sizes, int n_in,
                              void* d_out, int out_size, void* d_ws, size_t ws_size,
                              hipStream_t stream) {
    const float* pred    = (const float*)d_in[0];
    const float* y       = (const float*)d_in[1];
    const float* mid_pos = (const float*)d_in[2];
    const float* mid_vel = (const float*)d_in[3];
    const float* y_mean  = (const float*)d_in[4];
    const float* y_std   = (const float*)d_in[5];
    const float* h_p     = (const float*)d_in[6];
    const float* vol_p   = (const float*)d_in[7];
    // d_in[8] = rho_0 (cancels algebraically)
    const float* dt_p    = (const float*)d_in[9];
    const int*   nb_p    = (const int*)d_in[10];

    int N = in_sizes[0] / 3;
    float invN = 1.0f / (float)N;

    hipMemsetAsync(d_out, 0, sizeof(float), stream);   // graph-capturable node

    k_main<<<NBLK, TPB, 0, stream>>>(pred, y, mid_pos, mid_vel, y_mean, y_std,
                                     h_p, vol_p, dt_p, nb_p,
                                     (float*)d_out, N, invN);
}

// Round 11
// 19.941 us; speedup vs baseline: 6.1281x; 1.0633x over previous
//
#include <hip/hip_runtime.h>
#include <math.h>

#define TPB 1024
#define NBLK 243       // 9 x 9 x 3: home = z-column of 3 cells
#define NWAVE (TPB / 64)
#define NCELL 9
#define CAP 1024       // LDS staging capacity (column neighborhood mean ~380)
#define HCAP 1024      // home slot list capacity
#define PI_F 3.14159265358979323846f
#define EPS_F 1e-12f

__device__ __forceinline__ float wave_reduce(float v) {
#pragma unroll
    for (int off = 32; off > 0; off >>= 1) v += __shfl_down(v, off, 64);
    return v;
}

// valid on thread 0 only; all threads must call
__device__ __forceinline__ float block_reduce(float v, float* sbuf) {
    v = wave_reduce(v);
    int lane = threadIdx.x & 63;
    int wid  = threadIdx.x >> 6;
    if (lane == 0) sbuf[wid] = v;
    __syncthreads();
    float r = 0.0f;
    if (threadIdx.x == 0) {
        for (int w = 0; w < NWAVE; ++w) r += sbuf[w];
    }
    return r;
}

__device__ __forceinline__ int cell_coord(float x) {
    int c = (int)floorf(x * (float)NCELL);
    return min(max(c, 0), NCELL - 1);
}

__device__ __forceinline__ void pair_math(float xix, float xiy, float xiz,
                                          float vix, float viy, float viz,
                                          float ax, float ay, float az,
                                          float bx, float by, float bz,
                                          float inv_h, float h2,
                                          float& wacc, float& dacc) {
    float dx = xix - ax, dy = xiy - ay, dz = xiz - az;
    float d2 = fmaf(dx, dx, fmaf(dy, dy, dz * dz));
    float r2c = fmaxf(d2, EPS_F);
    float ir  = rsqrtf(r2c);
    float r   = r2c * ir;
    float q   = r * inv_h;
    bool inm = (d2 <= h2) && (q <= 1.0f);
    bool lo  = (q <= 0.5f);
    float q2 = q * q, om = 1.0f - q, om2 = om * om;
    float w  = lo ? fmaf(6.0f, q2 * q - q2, 1.0f) : 2.0f * om2 * om;
    wacc += inm ? w : 0.0f;
    float dw = lo ? q * fmaf(18.0f, q, -12.0f) : -6.0f * om2;
    dw = inm ? dw : 0.0f;
    float irm = (d2 > EPS_F) ? ir : 0.0f;
    float dvx = bx - vix, dvy = by - viy, dvz = bz - viz;
    float dot = fmaf(dvx, dx, fmaf(dvy, dy, dvz * dz));
    dacc = fmaf(dw * irm, dot, dacc);
}

__global__ void __launch_bounds__(TPB) k_main(
    const float* __restrict__ pred, const float* __restrict__ y,
    const float* __restrict__ mid_pos, const float* __restrict__ mid_vel,
    const float* __restrict__ y_mean, const float* __restrict__ y_std,
    const float* __restrict__ h_p, const float* __restrict__ vol_p,
    const float* __restrict__ dt_p, const int* __restrict__ nb_p,
    float* __restrict__ out, int N, float invN)
{
    __shared__ float4 sh4[CAP];      // pos.xyz, vel.x
    __shared__ float2 sh2[CAP];      // vel.yz
    __shared__ short  s_home[HCAP];  // LDS slot index of home particles
    __shared__ int    s_cnt, s_hcnt;
    __shared__ float  sred[NWAVE];

    int b   = blockIdx.x;
    int tid = threadIdx.x;
    int cx = b / 27, cy = (b / 3) % 9, czg = b % 3;
    int z0 = 3 * czg;                // home z cells: z0 .. z0+2

    if (tid == 0) { s_cnt = 0; s_hcnt = 0; }
    __syncthreads();

    int nb = nb_p[0];
    float inv_dt = 1.0f / dt_p[0];
    float ym0 = y_mean[0], ym1 = y_mean[1], ym2 = y_mean[2];
    float ys0 = y_std[0],  ys1 = y_std[1],  ys2 = y_std[2];

    bool do_l1 = (b == 0);
    float t1 = 0.0f;
    int ln = tid & 63;
    unsigned long long lmask = (1ull << ln) - 1ull;

    // ================= phase A: scan + stage =================
    if (N == TPB * 6) {
        // fast path: fully unrolled, all loads batched upfront (max MLP)
        float ppx[6], ppy[6], ppz[6], pvx[6], pvy[6], pvz[6];
        bool inN_[6];
        unsigned long long mN[6];
#pragma unroll
        for (int k = 0; k < 6; ++k) {
            int i = tid + k * TPB;
            float y0 = y[i * 3 + 0], y1 = y[i * 3 + 1], y2 = y[i * 3 + 2];
            float m0 = mid_pos[i * 3 + 0], m1 = mid_pos[i * 3 + 1], m2 = mid_pos[i * 3 + 2];
            float w0 = mid_vel[i * 3 + 0], w1 = mid_vel[i * 3 + 1], w2 = mid_vel[i * 3 + 2];
            if (do_l1) {
                float p0 = pred[i * 3 + 0], p1 = pred[i * 3 + 1], p2 = pred[i * 3 + 2];
                float d0 = y0 - p0, d1 = y1 - p1, d2 = y2 - p2;
                t1 = fmaf(d0, d0, fmaf(d1, d1, fmaf(d2, d2, t1)));
            }
            bool fluid = (i >= nb);
            float i0 = fluid ? fmaf(y0, ys0, ym0) : 0.0f;
            float i1 = fluid ? fmaf(y1, ys1, ym1) : 0.0f;
            float i2 = fluid ? fmaf(y2, ys2, ym2) : 0.0f;
            ppx[k] = m0 + i0; ppy[k] = m1 + i1; ppz[k] = m2 + i2;
            pvx[k] = w0 + i0 * inv_dt; pvy[k] = w1 + i1 * inv_dt; pvz[k] = w2 + i2 * inv_dt;
            int ix = cell_coord(ppx[k]), iy = cell_coord(ppy[k]), iz = cell_coord(ppz[k]);
            inN_[k] = (abs(ix - cx) <= 1) && (abs(iy - cy) <= 1) &&
                      (iz >= z0 - 1) && (iz <= z0 + 3);
            mN[k] = __ballot(inN_[k]);
        }
        // ONE LDS atomic per wave for all 6 sub-iterations
        int pre[6], tot = 0;
#pragma unroll
        for (int k = 0; k < 6; ++k) { pre[k] = tot; tot += __popcll(mN[k]); }
        int base = 0;
        if (ln == 0 && tot > 0) base = atomicAdd(&s_cnt, tot);
        base = __shfl(base, 0, 64);
#pragma unroll
        for (int k = 0; k < 6; ++k) {
            if (inN_[k]) {
                int slot = base + pre[k] + __popcll(mN[k] & lmask);
                if (slot < CAP) {
                    sh4[slot] = make_float4(ppx[k], ppy[k], ppz[k], pvx[k]);
                    sh2[slot] = make_float2(pvy[k], pvz[k]);
                }
            }
        }
    } else {
        // generic path
        for (int i = tid; i < N; i += TPB) {
            float y0 = y[i * 3 + 0], y1 = y[i * 3 + 1], y2 = y[i * 3 + 2];
            float m0 = mid_pos[i * 3 + 0], m1 = mid_pos[i * 3 + 1], m2 = mid_pos[i * 3 + 2];
            if (do_l1) {
                float p0 = pred[i * 3 + 0], p1 = pred[i * 3 + 1], p2 = pred[i * 3 + 2];
                float d0 = y0 - p0, d1 = y1 - p1, d2 = y2 - p2;
                t1 = fmaf(d0, d0, fmaf(d1, d1, fmaf(d2, d2, t1)));
            }
            bool fluid = (i >= nb);
            float i0 = fluid ? fmaf(y0, ys0, ym0) : 0.0f;
            float i1 = fluid ? fmaf(y1, ys1, ym1) : 0.0f;
            float i2 = fluid ? fmaf(y2, ys2, ym2) : 0.0f;
            float px = m0 + i0, py = m1 + i1, pz = m2 + i2;
            int ix = cell_coord(px), iy = cell_coord(py), iz = cell_coord(pz);
            bool inN = (abs(ix - cx) <= 1) && (abs(iy - cy) <= 1) &&
                       (iz >= z0 - 1) && (iz <= z0 + 3);
            unsigned long long mN = __ballot(inN);
            if (mN) {
                int base = 0;
                if (ln == 0) base = atomicAdd(&s_cnt, __popcll(mN));
                base = __shfl(base, 0, 64);
                if (inN) {
                    int slot = base + __popcll(mN & lmask);
                    if (slot < CAP) {
                        float v0 = mid_vel[i * 3 + 0] + i0 * inv_dt;
                        float v1 = mid_vel[i * 3 + 1] + i1 * inv_dt;
                        float v2 = mid_vel[i * 3 + 2] + i2 * inv_dt;
                        sh4[slot] = make_float4(px, py, pz, v0);
                        sh2[slot] = make_float2(v1, v2);
                    }
                }
            }
        }
    }
    if (do_l1) {                      // block-uniform branch
        float s1 = block_reduce(t1, sred);
        if (tid == 0) atomicAdd(out, s1 * invN);
    }
    __syncthreads();

    int T = s_cnt;
    bool staged = (T <= CAP);         // block-uniform

    float h = h_p[0], inv_h = 1.0f / h, h2 = h * h;
    float vol = vol_p[0];
    float sigma = 8.0f / (PI_F * h * h * h);
    int wv = tid >> 6;
    float acc = 0.0f;

    if (staged) {
        // ---- home compaction from staged data (1 ballot + 1 atomic per wave) ----
        bool isH = false;
        if (tid < T) {
            float4 a = sh4[tid];
            int ix = cell_coord(a.x), iy = cell_coord(a.y), iz = cell_coord(a.z);
            isH = (ix == cx) && (iy == cy) && (iz >= z0) && (iz <= z0 + 2);
        }
        unsigned long long mH = __ballot(isH);
        if (mH) {
            int hb = 0;
            if (ln == 0) hb = atomicAdd(&s_hcnt, __popcll(mH));
            hb = __shfl(hb, 0, 64);
            if (isH) s_home[hb + __popcll(mH & lmask)] = (short)tid;
        }
        __syncthreads();
        int H = s_hcnt;

        // ---- phase B: one wave per home particle vs staged neighborhood ----
        for (int hp = wv; hp < H; hp += NWAVE) {
            int hs = s_home[hp];
            float4 me4 = sh4[hs];
            float2 me2 = sh2[hs];
            float wacc = 0.0f, dacc = 0.0f;
            for (int j = ln; j < T; j += 64) {
                float4 a  = sh4[j];
                float2 b2 = sh2[j];
                pair_math(me4.x, me4.y, me4.z, me4.w, me2.x, me2.y,
                          a.x, a.y, a.z, a.w, b2.x, b2.y, inv_h, h2, wacc, dacc);
            }
            wacc = wave_reduce(wacc);
            dacc = wave_reduce(dacc);
            if (ln == 0) {
                acc += fabsf(fmaf(vol * sigma, wacc, -1.0f))
                     + fabsf(vol * (sigma / h) * dacc);
            }
        }
    } else {
        // overflow fallback (never for this input): O(N^2/waves) global path
        for (int i = wv; i < N; i += NWAVE) {
            float y0 = y[i * 3 + 0], y1 = y[i * 3 + 1], y2 = y[i * 3 + 2];
            bool fluid = (i >= nb);
            float i0 = fluid ? fmaf(y0, ys0, ym0) : 0.0f;
            float i1 = fluid ? fmaf(y1, ys1, ym1) : 0.0f;
            float i2 = fluid ? fmaf(y2, ys2, ym2) : 0.0f;
            float xix = mid_pos[i * 3 + 0] + i0;
            float xiy = mid_pos[i * 3 + 1] + i1;
            float xiz = mid_pos[i * 3 + 2] + i2;
            int ix = cell_coord(xix), iy = cell_coord(xiy), iz = cell_coord(xiz);
            bool isH = (ix == cx) && (iy == cy) && (iz >= z0) && (iz <= z0 + 2);
            if (!isH) continue;
            float vix = mid_vel[i * 3 + 0] + i0 * inv_dt;
            float viy = mid_vel[i * 3 + 1] + i1 * inv_dt;
            float viz = mid_vel[i * 3 + 2] + i2 * inv_dt;
            float wacc = 0.0f, dacc = 0.0f;
            for (int j = ln; j < N; j += 64) {
                float jy0 = y[j * 3 + 0], jy1 = y[j * 3 + 1], jy2 = y[j * 3 + 2];
                bool jf = (j >= nb);
                float j0 = jf ? fmaf(jy0, ys0, ym0) : 0.0f;
                float j1 = jf ? fmaf(jy1, ys1, ym1) : 0.0f;
                float j2 = jf ? fmaf(jy2, ys2, ym2) : 0.0f;
                float ax = mid_pos[j * 3 + 0] + j0;
                float ay = mid_pos[j * 3 + 1] + j1;
                float az = mid_pos[j * 3 + 2] + j2;
                float bx = mid_vel[j * 3 + 0] + j0 * inv_dt;
                float by = mid_vel[j * 3 + 1] + j1 * inv_dt;
                float bz = mid_vel[j * 3 + 2] + j2 * inv_dt;
                pair_math(xix, xiy, xiz, vix, viy, viz,
                          ax, ay, az, bx, by, bz, inv_h, h2, wacc, dacc);
            }
            wacc = wave_reduce(wacc);
            dacc = wave_reduce(dacc);
            if (ln == 0) {
                acc += fabsf(fmaf(vol * sigma, wacc, -1.0f))
                     + fabsf(vol * (sigma / h) * dacc);
            }
        }
        __syncthreads();
    }

    float tot = block_reduce(acc, sred);
    if (tid == 0) atomicAdd(out, 0.1f * invN * tot);   // device-scope atomic
}

extern "C" void kernel_launch(void* const* d_in, const int* in_sizes, int n_in,
                              void* d_out, int out_size, void* d_ws, size_t ws_size,
                              hipStream_t stream) {
    const float* pred    = (const float*)d_in[0];
    const float* y       = (const float*)d_in[1];
    const float* mid_pos = (const float*)d_in[2];
    const float* mid_vel = (const float*)d_in[3];
    const float* y_mean  = (const float*)d_in[4];
    const float* y_std   = (const float*)d_in[5];
    const float* h_p     = (const float*)d_in[6];
    const float* vol_p   = (const float*)d_in[7];
    // d_in[8] = rho_0 (cancels algebraically)
    const float* dt_p    = (const float*)d_in[9];
    const int*   nb_p    = (const int*)d_in[10];

    int N = in_sizes[0] / 3;
    float invN = 1.0f / (float)N;

    hipMemsetAsync(d_out, 0, sizeof(float), stream);

    k_main<<<NBLK, TPB, 0, stream>>>(pred, y, mid_pos, mid_vel, y_mean, y_std,
                                     h_p, vol_p, dt_p, nb_p,
                                     (float*)d_out, N, invN);
}